// Round 6
// baseline (356.066 us; speedup 1.0000x reference)
//
#include <hip/hip_runtime.h>
#include <hip/hip_bf16.h>
#include <stdint.h>

#define NROWS   32768     // 32*32*32
#define DIMD    256
#define NATOMS  1024

typedef short  bf16x8 __attribute__((ext_vector_type(8)));
typedef float  f32x4  __attribute__((ext_vector_type(4)));

__device__ __forceinline__ unsigned short bf16rne(float f) {
    unsigned u = __float_as_uint(f);
    u = u + 0x7FFFu + ((u >> 16) & 1u);
    return (unsigned short)(u >> 16);
}

// ---------------------------------------------------------------------------
// B prep: planes Bs[2][8][1024][32] bf16 (m: 0=rep,1=dict; kc; atom; k-in-32)
// K-major tiling -> each MFMA atom-fragment is a contiguous 1KB global read.
// Also dict row norms (fp32).
__global__ __launch_bounds__(256) void vq_bprep(
    const float* __restrict__ rep_w, const float* __restrict__ dict_w,
    unsigned short* __restrict__ Bs, float* __restrict__ dnorm)
{
    const int tid = threadIdx.x;
    const int atom = blockIdx.x * 32 + (tid >> 3);   // 32 blocks
    const int kc = tid & 7;                          // k-chunk of 32
    float ss = 0.f;
#pragma unroll
    for (int m = 0; m < 2; ++m) {
        const float* src = (m ? dict_w : rep_w) + (size_t)atom * DIMD + kc * 32;
        unsigned short* dst = Bs + (size_t)m * 262144 + (size_t)kc * 32768 + atom * 32;
#pragma unroll
        for (int q = 0; q < 8; ++q) {
            float4 v = *(const float4*)&src[q * 4];
            float fv[4] = {v.x, v.y, v.z, v.w};
            unsigned short a0[4];
#pragma unroll
            for (int e = 0; e < 4; ++e) {
                if (m) ss = fmaf(fv[e], fv[e], ss);
                a0[e] = bf16rne(fv[e]);
            }
            *(ushort4*)&dst[q * 4] = make_ushort4(a0[0], a0[1], a0[2], a0[3]);
        }
    }
    ss += __shfl_down(ss, 4, 8);
    ss += __shfl_down(ss, 2, 8);
    ss += __shfl_down(ss, 1, 8);
    if (kc == 0) dnorm[atom] = ss;
}

// ---------------------------------------------------------------------------
// register top-8 insert (u32 dist-key, f32 logit, u32 idx), sorted ascending.
// Strict < keeps incumbent on ties => lower index wins (ascending scan order).
__device__ __forceinline__ void ins8(unsigned u, float l, unsigned ix,
                                     unsigned (&kd)[8], float (&lv)[8], unsigned (&iv)[8]) {
    bool b[8];
#pragma unroll
    for (int j = 0; j < 8; ++j) b[j] = u < kd[j];
#pragma unroll
    for (int j = 7; j >= 1; --j) {
        kd[j] = b[j] ? (b[j - 1] ? kd[j - 1] : u)  : kd[j];
        lv[j] = b[j] ? (b[j - 1] ? lv[j - 1] : l)  : lv[j];
        iv[j] = b[j] ? (b[j - 1] ? iv[j - 1] : ix) : iv[j];
    }
    if (b[0]) { kd[0] = u; lv[0] = l; iv[0] = ix; }
}

// u64 merge insert (key = dist<<32 | idx), payload logit
__device__ __forceinline__ void ins8m(unsigned long long ck, float cl,
                                      unsigned long long (&key)[8], float (&lg)[8]) {
    bool b[8];
#pragma unroll
    for (int j = 0; j < 8; ++j) b[j] = ck < key[j];
#pragma unroll
    for (int j = 7; j >= 1; --j) {
        key[j] = b[j] ? (b[j - 1] ? key[j - 1] : ck) : key[j];
        lg[j]  = b[j] ? (b[j - 1] ? lg[j - 1]  : cl) : lg[j];
    }
    if (b[0]) { key[0] = ck; lg[0] = cl; }
}

// ---------------------------------------------------------------------------
// Main: dual GEMM (logits+dists, bf16) with swapped MFMA operands; each lane
// owns one flat-row's online softmax-sum + top-8 in registers. No LDS in hot
// loop. Block = 64 rows, 4 waves x 16 rows, grid 512 -> 2-3 blocks/CU.
// Epilogue: in-wave shfl merge of the 4 per-part states, fill + scatter.
__global__ __launch_bounds__(256, 3) void vq_main(
    const float* __restrict__ z_e, const unsigned short* __restrict__ Bs,
    const float* __restrict__ rep_b, const float* __restrict__ dnorm,
    float* __restrict__ rep_sparse, int* __restrict__ idx_out,
    float* __restrict__ w_out, int* __restrict__ counts)
{
    __shared__ float rbS[1024];
    __shared__ float dnS[1024];

    const int tid = threadIdx.x;
    const int lane = tid & 63, w = tid >> 6;
    const int c = lane & 15, lg = lane >> 4;
    const int row0 = blockIdx.x * 64;
    const int bb = row0 >> 10, hw0 = row0 & 1023;

    for (int i = tid; i < 1024; i += 256) { rbS[i] = rep_b[i]; dnS[i] = dnorm[i]; }

    const char* pL = (const char*)Bs;             // rep plane  [8][1024][32]
    const char* pD = (const char*)Bs + 524288;    // dict plane

    // first B tile (atoms 0..15): frag = 16 atoms x 32k, contiguous 1KB
    bf16x8 bL[8], bD[8];
    {
        const int off = (c << 6) + (lg << 4);
#pragma unroll
        for (int kc = 0; kc < 8; ++kc) {
            bL[kc] = *(const bf16x8*)(pL + ((size_t)kc << 16) + off);
            bD[kc] = *(const bf16x8*)(pD + ((size_t)kc << 16) + off);
        }
    }

    // A: wave's 16 rows (w*16 + c), k = kc*32 + lg*8 + e, bf16 1-term
    bf16x8 A[8];
    {
        const float* zb = z_e + (size_t)bb * 262144 + hw0 + w * 16 + c;
#pragma unroll
        for (int kc = 0; kc < 8; ++kc) {
            float f[8];
#pragma unroll
            for (int e = 0; e < 8; ++e)
                f[e] = zb[(size_t)(kc * 32 + lg * 8 + e) * 1024];
#pragma unroll
            for (int e = 0; e < 8; ++e)
                A[kc][e] = (short)bf16rne(f[e]);
        }
    }
    __syncthreads();   // tables staged

    // per-lane online state (part lg of row w*16+c)
    unsigned kd[8], iv[8];
    float lv[8];
    float sume0 = 0.f, sume1 = 0.f;
#pragma unroll
    for (int j = 0; j < 8; ++j) { kd[j] = 0xFFFFFFFFu; iv[j] = 0u; lv[j] = 0.f; }

    for (int it = 0; it < 64; ++it) {
        __builtin_amdgcn_s_barrier();   // align waves for L1 tile reuse

        f32x4 aL = {0.f, 0.f, 0.f, 0.f};
        f32x4 aD = {0.f, 0.f, 0.f, 0.f};
        // D[atom][flatrow]: A-operand = atom frag, B-operand = flat-row frag
#pragma unroll
        for (int kc = 0; kc < 8; ++kc) {
            aL = __builtin_amdgcn_mfma_f32_16x16x32_bf16(bL[kc], A[kc], aL, 0, 0, 0);
            aD = __builtin_amdgcn_mfma_f32_16x16x32_bf16(bD[kc], A[kc], aD, 0, 0, 0);
        }

        // prefetch next tile (regs free after last MFMA read)
        if (it < 63) {
            const int off = (((it + 1) * 16 + c) << 6) + (lg << 4);
#pragma unroll
            for (int kc = 0; kc < 8; ++kc) {
                bL[kc] = *(const bf16x8*)(pL + ((size_t)kc << 16) + off);
                bD[kc] = *(const bf16x8*)(pD + ((size_t)kc << 16) + off);
            }
        }

        // in-register scan: lane's flat-row = w*16+c; atoms it*16 + lg*4 + q
#pragma unroll
        for (int q = 0; q < 4; ++q) {
            const int atom = (it << 4) + (lg << 2) + q;
            const float l = aL[q] + rbS[atom];
            const float v = dnS[atom] - 2.0f * aD[q];
            if (q & 1) sume1 += __expf(l); else sume0 += __expf(l);
            unsigned u = __float_as_uint(v);
            u ^= ((unsigned)((int)u >> 31) | 0x80000000u);
            if (u < kd[7]) ins8(u, l, (unsigned)atom, kd, lv, iv);
        }
    }
    float sume = sume0 + sume1;

    // ---- in-wave merge: row c's 4 parts live in lanes c, c+16, c+32, c+48
    unsigned long long K[8];
    float L[8];
#pragma unroll
    for (int j = 0; j < 8; ++j) { K[j] = ((unsigned long long)kd[j] << 32) | iv[j]; L[j] = lv[j]; }

#pragma unroll
    for (int half = 32; half >= 16; half >>= 1) {
        const int src = (lane + half) & 63;
        unsigned long long Ko[8];
        float Lo[8];
#pragma unroll
        for (int j = 0; j < 8; ++j) {
            const unsigned hi = (unsigned)__shfl((int)(K[j] >> 32), src, 64);
            const unsigned lo = (unsigned)__shfl((int)(K[j] & 0xffffffffu), src, 64);
            Ko[j] = ((unsigned long long)hi << 32) | lo;
            Lo[j] = __shfl(L[j], src, 64);
        }
        const float so = __shfl(sume, src, 64);
        if (lane < half) {
            sume += so;
#pragma unroll
            for (int t = 0; t < 8; ++t)
                if (Ko[t] < K[7]) ins8m(Ko[t], Lo[t], K, L);
        }
    }
    // lanes 0..15 of each wave now hold the merged row state

    // zero-fill this block's 64 rows of rep_sparse (replaces memset kernel)
    {
        float4 z4 = {0.f, 0.f, 0.f, 0.f};
        float4* rp4 = (float4*)rep_sparse + (size_t)row0 * (NATOMS / 4) + tid;
        for (int r = 0; r < 64; ++r)
            rp4[(size_t)r * (NATOMS / 4)] = z4;
    }
    __syncthreads();   // drains the zero stores before scatter

    if (lane < 16) {
        const int row = row0 + w * 16 + c;
        const float inv = 0.125f / sume;   // softmax / SPARSITY
#pragma unroll
        for (int j = 0; j < 8; ++j) {
            const int gidx = (int)(K[j] & 0x3ffull);
            const float wv = __expf(L[j]) * inv;
            idx_out[row * 8 + j] = gidx;
            w_out[row * 8 + j] = wv;
            rep_sparse[(size_t)row * NATOMS + gidx] = wv;
            atomicAdd(&counts[gidx], 1);
        }
    }
}

// ---------------------------------------------------------------------------
// Reconstruct z_dl, write z_st (NCHW), accumulate squared-error partials.
__global__ __launch_bounds__(256, 2) void vq_recon(
    const float* __restrict__ z_e, const float* __restrict__ dict_w,
    const int* __restrict__ idx_in, const float* __restrict__ w_in,
    float* __restrict__ z_st, float* __restrict__ partials)
{
    __shared__ float zdl[32][257];
    __shared__ float red[256];
    const int tid = threadIdx.x;
    const int row0 = blockIdx.x * 32;

    for (int r = 0; r < 32; ++r) {
        const int row = row0 + r;
        float acc = 0.f;
#pragma unroll
        for (int j = 0; j < 8; ++j) {
            const int ix = idx_in[row * 8 + j];
            const float wv = w_in[row * 8 + j];
            acc = fmaf(wv, dict_w[(size_t)ix * DIMD + tid], acc);
        }
        zdl[r][tid] = acc;
    }
    __syncthreads();

    const int bb = row0 >> 10, hw0 = row0 & 1023;
    const float* zb = z_e + (size_t)bb * (DIMD * 1024) + hw0;
    float* ob = z_st + (size_t)bb * (DIMD * 1024) + hw0;
    const int m = tid & 31, dg = tid >> 5;
    float sacc = 0.f;
    for (int itr = 0; itr < 32; ++itr) {
        const int d = itr * 8 + dg;
        const float ze = zb[(size_t)d * 1024 + m];
        const float zd = zdl[m][d];
        const float diff = zd - ze;
        ob[(size_t)d * 1024 + m] = ze + diff;   // reference rounding path
        sacc = fmaf(diff, diff, sacc);
    }
    red[tid] = sacc;
    __syncthreads();
    for (int s = 128; s > 0; s >>= 1) {
        if (tid < s) red[tid] += red[tid + s];
        __syncthreads();
    }
    if (tid == 0) partials[blockIdx.x] = red[0];
}

// ---------------------------------------------------------------------------
// Finalize: loss and perplexity (deterministic fixed-order reductions)
__global__ void vq_final(const float* __restrict__ partials,
                         const int* __restrict__ counts,
                         float* __restrict__ out_loss, float* __restrict__ out_perp)
{
    __shared__ double dred[256];
    __shared__ float fred[256];
    const int tid = threadIdx.x;
    double s = 0.0;
    for (int i = tid; i < 1024; i += 256) s += (double)partials[i];
    dred[tid] = s;
    __syncthreads();
    for (int st = 128; st > 0; st >>= 1) {
        if (tid < st) dred[tid] += dred[tid + st];
        __syncthreads();
    }
    float ps = 0.f;
    for (int i = tid; i < NATOMS; i += 256) {
        const float p = (float)counts[i] * (1.0f / 262144.0f);
        ps += p * logf(p + 1e-10f);
    }
    fred[tid] = ps;
    __syncthreads();
    for (int st = 128; st > 0; st >>= 1) {
        if (tid < st) fred[tid] += fred[tid + st];
        __syncthreads();
    }
    if (tid == 0) {
        *out_loss = 0.25f * (float)(dred[0] / 8388608.0);
        *out_perp = expf(-fred[0]);
    }
}

// ---------------------------------------------------------------------------
extern "C" void kernel_launch(void* const* d_in, const int* in_sizes, int n_in,
                              void* d_out, int out_size, void* d_ws, size_t ws_size,
                              hipStream_t stream) {
    const float* z_e    = (const float*)d_in[0];
    const float* dict_w = (const float*)d_in[1];
    const float* rep_w  = (const float*)d_in[2];
    const float* rep_b  = (const float*)d_in[3];

    float* out = (float*)d_out;
    float* out_loss   = out;                      // [0]
    float* z_st       = out + 1;                  // [1 .. 8388608]
    float* out_perp   = out + 1 + 8388608;        // [8388609]
    float* rep_sparse = out + 2 + 8388608;        // [8388610 ..] 32768x1024

    // Bs scratch (1 MB, 2 planes) parked INSIDE the z_st output region
    // (offset 16 MB). vq_recon rewrites all of z_st after vq_main finishes,
    // so no live data is clobbered and nothing leaks across calls.
    unsigned short* Bs = (unsigned short*)((((uintptr_t)(z_st + 4194304)) + 255) & ~(uintptr_t)255);

    char* ws = (char*)d_ws;
    int*   idx_out  = (int*)ws;                             // 1 MB
    float* w_out    = (float*)(ws + (1 << 20));             // 1 MB
    int*   counts   = (int*)(ws + (2 << 20));               // 4 KB
    float* dnorm    = (float*)(ws + (2 << 20) + 4096);      // 4 KB
    float* partials = (float*)(ws + (2 << 20) + 8192);      // 4 KB

    hipMemsetAsync(counts, 0, NATOMS * sizeof(int), stream);

    vq_bprep<<<32, 256, 0, stream>>>(rep_w, dict_w, Bs, dnorm);
    vq_main<<<NROWS / 64, 256, 0, stream>>>(z_e, Bs, rep_b, dnorm,
                                            rep_sparse, idx_out, w_out, counts);
    vq_recon<<<NROWS / 32, 256, 0, stream>>>(z_e, dict_w, idx_out, w_out, z_st, partials);
    vq_final<<<1, 256, 0, stream>>>(partials, counts, out_loss, out_perp);
}

// Round 7
// 316.589 us; speedup vs baseline: 1.1247x; 1.1247x over previous
//
#include <hip/hip_runtime.h>
#include <hip/hip_bf16.h>
#include <stdint.h>

#define NROWS   32768     // 32*32*32
#define DIMD    256
#define NATOMS  1024

typedef short  bf16x8 __attribute__((ext_vector_type(8)));
typedef float  f32x4  __attribute__((ext_vector_type(4)));

__device__ __forceinline__ unsigned short bf16rne(float f) {
    unsigned u = __float_as_uint(f);
    u = u + 0x7FFFu + ((u >> 16) & 1u);
    return (unsigned short)(u >> 16);
}

// ---------------------------------------------------------------------------
// B prep: planes Bs[2][8][1024][32] bf16 (m: 0=rep,1=dict; kc; atom; k-in-32)
// K-major tiling -> each MFMA atom-fragment is a contiguous 1KB global read.
// Also dict row norms (fp32).
__global__ __launch_bounds__(256) void vq_bprep(
    const float* __restrict__ rep_w, const float* __restrict__ dict_w,
    unsigned short* __restrict__ Bs, float* __restrict__ dnorm)
{
    const int tid = threadIdx.x;
    const int atom = blockIdx.x * 32 + (tid >> 3);   // 32 blocks
    const int kc = tid & 7;                          // k-chunk of 32
    float ss = 0.f;
#pragma unroll
    for (int m = 0; m < 2; ++m) {
        const float* src = (m ? dict_w : rep_w) + (size_t)atom * DIMD + kc * 32;
        unsigned short* dst = Bs + (size_t)m * 262144 + (size_t)kc * 32768 + atom * 32;
#pragma unroll
        for (int q = 0; q < 8; ++q) {
            float4 v = *(const float4*)&src[q * 4];
            float fv[4] = {v.x, v.y, v.z, v.w};
            unsigned short a0[4];
#pragma unroll
            for (int e = 0; e < 4; ++e) {
                if (m) ss = fmaf(fv[e], fv[e], ss);
                a0[e] = bf16rne(fv[e]);
            }
            *(ushort4*)&dst[q * 4] = make_ushort4(a0[0], a0[1], a0[2], a0[3]);
        }
    }
    ss += __shfl_down(ss, 4, 8);
    ss += __shfl_down(ss, 2, 8);
    ss += __shfl_down(ss, 1, 8);
    if (kc == 0) dnorm[atom] = ss;
}

// ---------------------------------------------------------------------------
// register top-8 insert (u32 dist-key, f32 logit, u32 idx), sorted ascending.
// Strict < keeps incumbent on ties => lower index wins (ascending scan order).
__device__ __forceinline__ void ins8(unsigned u, float l, unsigned ix,
                                     unsigned (&kd)[8], float (&lv)[8], unsigned (&iv)[8]) {
    bool b[8];
#pragma unroll
    for (int j = 0; j < 8; ++j) b[j] = u < kd[j];
#pragma unroll
    for (int j = 7; j >= 1; --j) {
        kd[j] = b[j] ? (b[j - 1] ? kd[j - 1] : u)  : kd[j];
        lv[j] = b[j] ? (b[j - 1] ? lv[j - 1] : l)  : lv[j];
        iv[j] = b[j] ? (b[j - 1] ? iv[j - 1] : ix) : iv[j];
    }
    if (b[0]) { kd[0] = u; lv[0] = l; iv[0] = ix; }
}

// u64 merge insert (key = dist<<32 | idx), payload logit
__device__ __forceinline__ void ins8m(unsigned long long ck, float cl,
                                      unsigned long long (&key)[8], float (&lg)[8]) {
    bool b[8];
#pragma unroll
    for (int j = 0; j < 8; ++j) b[j] = ck < key[j];
#pragma unroll
    for (int j = 7; j >= 1; --j) {
        key[j] = b[j] ? (b[j - 1] ? key[j - 1] : ck) : key[j];
        lg[j]  = b[j] ? (b[j - 1] ? lg[j - 1]  : cl) : lg[j];
    }
    if (b[0]) { key[0] = ck; lg[0] = cl; }
}

// ---------------------------------------------------------------------------
// Main: dual GEMM (logits+dists, bf16) with swapped MFMA operands; each lane
// owns one flat-row's online softmax-sum + top-8 in registers. Atom axis is
// split across 2 waves (512 atoms each) -> 4096 waves total, 3 blocks/CU.
// Block = 32 rows, 4 waves: w = rh*2 + ah (rh: row-group of 16, ah: atom half).
// No barrier in the hot loop (free-running waves; B tiles L1/L2-resident).
__global__ __launch_bounds__(256, 3) void vq_main(
    const float* __restrict__ z_e, const unsigned short* __restrict__ Bs,
    const float* __restrict__ rep_b, const float* __restrict__ dnorm,
    float* __restrict__ rep_sparse, int* __restrict__ idx_out,
    float* __restrict__ w_out, int* __restrict__ counts)
{
    __shared__ float rbS[1024];
    __shared__ float dnS[1024];
    __shared__ unsigned long long mK[2][16][8];
    __shared__ float mL[2][16][8];
    __shared__ float mS[2][16];

    const int tid = threadIdx.x;
    const int lane = tid & 63, w = tid >> 6;
    const int rh = w >> 1, ah = w & 1;
    const int c = lane & 15, lg = lane >> 4;
    const int row0 = blockIdx.x * 32;
    const int bb = row0 >> 10, hw0 = row0 & 1023;

    for (int i = tid; i < 1024; i += 256) { rbS[i] = rep_b[i]; dnS[i] = dnorm[i]; }

    const char* pL = (const char*)Bs;             // rep plane  [8][1024][32]
    const char* pD = (const char*)Bs + 524288;    // dict plane
    const int abase = ah << 9;                    // this wave's atom-half base

    // first B tile (atoms abase..abase+15): frag = 16 atoms x 32k, 1KB each
    bf16x8 bL[8], bD[8];
    {
        const int off = ((abase + c) << 6) + (lg << 4);
#pragma unroll
        for (int kc = 0; kc < 8; ++kc) {
            bL[kc] = *(const bf16x8*)(pL + ((size_t)kc << 16) + off);
            bD[kc] = *(const bf16x8*)(pD + ((size_t)kc << 16) + off);
        }
    }

    // A: wave's 16 rows (rh*16 + c), k = kc*32 + lg*8 + e, bf16 1-term
    bf16x8 A[8];
    {
        const float* zb = z_e + (size_t)bb * 262144 + hw0 + rh * 16 + c;
#pragma unroll
        for (int kc = 0; kc < 8; ++kc) {
            float f[8];
#pragma unroll
            for (int e = 0; e < 8; ++e)
                f[e] = zb[(size_t)(kc * 32 + lg * 8 + e) * 1024];
#pragma unroll
            for (int e = 0; e < 8; ++e)
                A[kc][e] = (short)bf16rne(f[e]);
        }
    }
    __syncthreads();   // tables staged

    // per-lane online state (part lg of row rh*16+c, atom half ah)
    unsigned kd[8], iv[8];
    float lv[8];
    float sume0 = 0.f, sume1 = 0.f;
#pragma unroll
    for (int j = 0; j < 8; ++j) { kd[j] = 0xFFFFFFFFu; iv[j] = 0u; lv[j] = 0.f; }

    for (int it = 0; it < 32; ++it) {
        f32x4 aL = {0.f, 0.f, 0.f, 0.f};
        f32x4 aD = {0.f, 0.f, 0.f, 0.f};
        // D[atom][flatrow]: A-operand = atom frag, B-operand = flat-row frag
#pragma unroll
        for (int kc = 0; kc < 8; ++kc) {
            aL = __builtin_amdgcn_mfma_f32_16x16x32_bf16(bL[kc], A[kc], aL, 0, 0, 0);
            aD = __builtin_amdgcn_mfma_f32_16x16x32_bf16(bD[kc], A[kc], aD, 0, 0, 0);
        }

        // prefetch next tile (regs free after last MFMA read)
        if (it < 31) {
            const int off = ((abase + (it + 1) * 16 + c) << 6) + (lg << 4);
#pragma unroll
            for (int kc = 0; kc < 8; ++kc) {
                bL[kc] = *(const bf16x8*)(pL + ((size_t)kc << 16) + off);
                bD[kc] = *(const bf16x8*)(pD + ((size_t)kc << 16) + off);
            }
        }

        // in-register scan: lane's flat-row = rh*16+c; atoms abase+it*16+lg*4+q
#pragma unroll
        for (int q = 0; q < 4; ++q) {
            const int atom = abase + (it << 4) + (lg << 2) + q;
            const float l = aL[q] + rbS[atom];
            const float v = dnS[atom] - 2.0f * aD[q];
            if (q & 1) sume1 += __expf(l); else sume0 += __expf(l);
            unsigned u = __float_as_uint(v);
            u ^= ((unsigned)((int)u >> 31) | 0x80000000u);
            if (u < kd[7]) ins8(u, l, (unsigned)atom, kd, lv, iv);
        }
    }
    float sume = sume0 + sume1;

    // ---- in-wave merge: row c's 4 parts live in lanes c, c+16, c+32, c+48
    unsigned long long K[8];
    float L[8];
#pragma unroll
    for (int j = 0; j < 8; ++j) { K[j] = ((unsigned long long)kd[j] << 32) | iv[j]; L[j] = lv[j]; }

#pragma unroll
    for (int half = 32; half >= 16; half >>= 1) {
        const int src = (lane + half) & 63;
        unsigned long long Ko[8];
        float Lo[8];
#pragma unroll
        for (int j = 0; j < 8; ++j) {
            const unsigned hi = (unsigned)__shfl((int)(K[j] >> 32), src, 64);
            const unsigned lo = (unsigned)__shfl((int)(K[j] & 0xffffffffu), src, 64);
            Ko[j] = ((unsigned long long)hi << 32) | lo;
            Lo[j] = __shfl(L[j], src, 64);
        }
        const float so = __shfl(sume, src, 64);
        if (lane < half) {
            sume += so;
#pragma unroll
            for (int t = 0; t < 8; ++t)
                if (Ko[t] < K[7]) ins8m(Ko[t], Lo[t], K, L);
        }
    }
    // lanes 0..15 hold this wave's merged row state (one atom half)

    // ah=1 waves publish their half to LDS
    if (ah == 1 && lane < 16) {
#pragma unroll
        for (int j = 0; j < 8; ++j) { mK[rh][c][j] = K[j]; mL[rh][c][j] = L[j]; }
        mS[rh][c] = sume;
    }
    __syncthreads();

    // zero-fill this block's 32 rows of rep_sparse (replaces memset kernel)
    {
        float4 z4 = {0.f, 0.f, 0.f, 0.f};
        float4* rp4 = (float4*)rep_sparse + (size_t)row0 * (NATOMS / 4) + tid;
        for (int r = 0; r < 32; ++r)
            rp4[(size_t)r * (NATOMS / 4)] = z4;
    }
    __syncthreads();   // drains the zero stores before scatter

    // ah=0 waves: merge the other half, finalize, scatter
    if (ah == 0 && lane < 16) {
#pragma unroll
        for (int t = 0; t < 8; ++t) {
            const unsigned long long ck = mK[rh][c][t];
            if (ck < K[7]) ins8m(ck, mL[rh][c][t], K, L);
        }
        sume += mS[rh][c];
        const int row = row0 + rh * 16 + c;
        const float inv = 0.125f / sume;   // softmax / SPARSITY
#pragma unroll
        for (int j = 0; j < 8; ++j) {
            const int gidx = (int)(K[j] & 0x3ffull);
            const float wv = __expf(L[j]) * inv;
            idx_out[row * 8 + j] = gidx;
            w_out[row * 8 + j] = wv;
            rep_sparse[(size_t)row * NATOMS + gidx] = wv;
            atomicAdd(&counts[gidx], 1);
        }
    }
}

// ---------------------------------------------------------------------------
// Reconstruct z_dl, write z_st (NCHW), accumulate squared-error partials.
__global__ __launch_bounds__(256, 2) void vq_recon(
    const float* __restrict__ z_e, const float* __restrict__ dict_w,
    const int* __restrict__ idx_in, const float* __restrict__ w_in,
    float* __restrict__ z_st, float* __restrict__ partials)
{
    __shared__ float zdl[32][257];
    __shared__ float red[256];
    const int tid = threadIdx.x;
    const int row0 = blockIdx.x * 32;

    for (int r = 0; r < 32; ++r) {
        const int row = row0 + r;
        float acc = 0.f;
#pragma unroll
        for (int j = 0; j < 8; ++j) {
            const int ix = idx_in[row * 8 + j];
            const float wv = w_in[row * 8 + j];
            acc = fmaf(wv, dict_w[(size_t)ix * DIMD + tid], acc);
        }
        zdl[r][tid] = acc;
    }
    __syncthreads();

    const int bb = row0 >> 10, hw0 = row0 & 1023;
    const float* zb = z_e + (size_t)bb * (DIMD * 1024) + hw0;
    float* ob = z_st + (size_t)bb * (DIMD * 1024) + hw0;
    const int m = tid & 31, dg = tid >> 5;
    float sacc = 0.f;
    for (int itr = 0; itr < 32; ++itr) {
        const int d = itr * 8 + dg;
        const float ze = zb[(size_t)d * 1024 + m];
        const float zd = zdl[m][d];
        const float diff = zd - ze;
        ob[(size_t)d * 1024 + m] = ze + diff;   // reference rounding path
        sacc = fmaf(diff, diff, sacc);
    }
    red[tid] = sacc;
    __syncthreads();
    for (int s = 128; s > 0; s >>= 1) {
        if (tid < s) red[tid] += red[tid + s];
        __syncthreads();
    }
    if (tid == 0) partials[blockIdx.x] = red[0];
}

// ---------------------------------------------------------------------------
// Finalize: loss and perplexity (deterministic fixed-order reductions)
__global__ void vq_final(const float* __restrict__ partials,
                         const int* __restrict__ counts,
                         float* __restrict__ out_loss, float* __restrict__ out_perp)
{
    __shared__ double dred[256];
    __shared__ float fred[256];
    const int tid = threadIdx.x;
    double s = 0.0;
    for (int i = tid; i < 1024; i += 256) s += (double)partials[i];
    dred[tid] = s;
    __syncthreads();
    for (int st = 128; st > 0; st >>= 1) {
        if (tid < st) dred[tid] += dred[tid + st];
        __syncthreads();
    }
    float ps = 0.f;
    for (int i = tid; i < NATOMS; i += 256) {
        const float p = (float)counts[i] * (1.0f / 262144.0f);
        ps += p * logf(p + 1e-10f);
    }
    fred[tid] = ps;
    __syncthreads();
    for (int st = 128; st > 0; st >>= 1) {
        if (tid < st) fred[tid] += fred[tid + st];
        __syncthreads();
    }
    if (tid == 0) {
        *out_loss = 0.25f * (float)(dred[0] / 8388608.0);
        *out_perp = expf(-fred[0]);
    }
}

// ---------------------------------------------------------------------------
extern "C" void kernel_launch(void* const* d_in, const int* in_sizes, int n_in,
                              void* d_out, int out_size, void* d_ws, size_t ws_size,
                              hipStream_t stream) {
    const float* z_e    = (const float*)d_in[0];
    const float* dict_w = (const float*)d_in[1];
    const float* rep_w  = (const float*)d_in[2];
    const float* rep_b  = (const float*)d_in[3];

    float* out = (float*)d_out;
    float* out_loss   = out;                      // [0]
    float* z_st       = out + 1;                  // [1 .. 8388608]
    float* out_perp   = out + 1 + 8388608;        // [8388609]
    float* rep_sparse = out + 2 + 8388608;        // [8388610 ..] 32768x1024

    // Bs scratch (1 MB, 2 planes) parked INSIDE the z_st output region
    // (offset 16 MB). vq_recon rewrites all of z_st after vq_main finishes,
    // so no live data is clobbered and nothing leaks across calls.
    unsigned short* Bs = (unsigned short*)((((uintptr_t)(z_st + 4194304)) + 255) & ~(uintptr_t)255);

    char* ws = (char*)d_ws;
    int*   idx_out  = (int*)ws;                             // 1 MB
    float* w_out    = (float*)(ws + (1 << 20));             // 1 MB
    int*   counts   = (int*)(ws + (2 << 20));               // 4 KB
    float* dnorm    = (float*)(ws + (2 << 20) + 4096);      // 4 KB
    float* partials = (float*)(ws + (2 << 20) + 8192);      // 4 KB

    hipMemsetAsync(counts, 0, NATOMS * sizeof(int), stream);

    vq_bprep<<<32, 256, 0, stream>>>(rep_w, dict_w, Bs, dnorm);
    vq_main<<<NROWS / 32, 256, 0, stream>>>(z_e, Bs, rep_b, dnorm,
                                            rep_sparse, idx_out, w_out, counts);
    vq_recon<<<NROWS / 32, 256, 0, stream>>>(z_e, dict_w, idx_out, w_out, z_st, partials);
    vq_final<<<1, 256, 0, stream>>>(partials, counts, out_loss, out_perp);
}

// Round 9
// 297.500 us; speedup vs baseline: 1.1969x; 1.0642x over previous
//
#include <hip/hip_runtime.h>
#include <hip/hip_bf16.h>
#include <stdint.h>

#define NROWS   32768     // 32*32*32
#define DIMD    256
#define NATOMS  1024

typedef short  bf16x8 __attribute__((ext_vector_type(8)));
typedef float  f32x4  __attribute__((ext_vector_type(4)));

__device__ __forceinline__ unsigned short bf16rne(float f) {
    unsigned u = __float_as_uint(f);
    u = u + 0x7FFFu + ((u >> 16) & 1u);
    return (unsigned short)(u >> 16);
}

// ---------------------------------------------------------------------------
// B prep: planes Bs[2][8][1024][32] bf16 (m: 0=rep,1=dict; kc; atom; k-in-32)
// K-major tiling -> each MFMA atom-fragment is a contiguous 1KB global read.
// Also dict row norms (fp32).
__global__ __launch_bounds__(256) void vq_bprep(
    const float* __restrict__ rep_w, const float* __restrict__ dict_w,
    unsigned short* __restrict__ Bs, float* __restrict__ dnorm)
{
    const int tid = threadIdx.x;
    const int atom = blockIdx.x * 32 + (tid >> 3);   // 32 blocks
    const int kc = tid & 7;                          // k-chunk of 32
    float ss = 0.f;
#pragma unroll
    for (int m = 0; m < 2; ++m) {
        const float* src = (m ? dict_w : rep_w) + (size_t)atom * DIMD + kc * 32;
        unsigned short* dst = Bs + (size_t)m * 262144 + (size_t)kc * 32768 + atom * 32;
#pragma unroll
        for (int q = 0; q < 8; ++q) {
            float4 v = *(const float4*)&src[q * 4];
            float fv[4] = {v.x, v.y, v.z, v.w};
            unsigned short a0[4];
#pragma unroll
            for (int e = 0; e < 4; ++e) {
                if (m) ss = fmaf(fv[e], fv[e], ss);
                a0[e] = bf16rne(fv[e]);
            }
            *(ushort4*)&dst[q * 4] = make_ushort4(a0[0], a0[1], a0[2], a0[3]);
        }
    }
    ss += __shfl_down(ss, 4, 8);
    ss += __shfl_down(ss, 2, 8);
    ss += __shfl_down(ss, 1, 8);
    if (kc == 0) dnorm[atom] = ss;
}

// ---------------------------------------------------------------------------
// register top-8 insert (u32 dist-key, f32 logit, u32 idx), sorted ascending.
// Strict < keeps incumbent on ties => lower index wins (ascending scan order).
__device__ __forceinline__ void ins8(unsigned u, float l, unsigned ix,
                                     unsigned (&kd)[8], float (&lv)[8], unsigned (&iv)[8]) {
    bool b[8];
#pragma unroll
    for (int j = 0; j < 8; ++j) b[j] = u < kd[j];
#pragma unroll
    for (int j = 7; j >= 1; --j) {
        kd[j] = b[j] ? (b[j - 1] ? kd[j - 1] : u)  : kd[j];
        lv[j] = b[j] ? (b[j - 1] ? lv[j - 1] : l)  : lv[j];
        iv[j] = b[j] ? (b[j - 1] ? iv[j - 1] : ix) : iv[j];
    }
    if (b[0]) { kd[0] = u; lv[0] = l; iv[0] = ix; }
}

// u64 merge insert (key = dist<<32 | idx), payload logit
__device__ __forceinline__ void ins8m(unsigned long long ck, float cl,
                                      unsigned long long (&key)[8], float (&lg)[8]) {
    bool b[8];
#pragma unroll
    for (int j = 0; j < 8; ++j) b[j] = ck < key[j];
#pragma unroll
    for (int j = 7; j >= 1; --j) {
        key[j] = b[j] ? (b[j - 1] ? key[j - 1] : ck) : key[j];
        lg[j]  = b[j] ? (b[j - 1] ? lg[j - 1]  : cl) : lg[j];
    }
    if (b[0]) { key[0] = ck; lg[0] = cl; }
}

// in-wave shfl merge over lane-groups (parts in lanes c, c+16, c+32, c+48)
__device__ __forceinline__ void wave_merge(int lane, unsigned long long (&K)[8],
                                           float (&L)[8], float& sume) {
#pragma unroll
    for (int half = 32; half >= 16; half >>= 1) {
        const int src = (lane + half) & 63;
        unsigned long long Ko[8];
        float Lo[8];
#pragma unroll
        for (int j = 0; j < 8; ++j) {
            const unsigned hi = (unsigned)__shfl((int)(K[j] >> 32), src, 64);
            const unsigned lo = (unsigned)__shfl((int)(K[j] & 0xffffffffu), src, 64);
            Ko[j] = ((unsigned long long)hi << 32) | lo;
            Lo[j] = __shfl(L[j], src, 64);
        }
        const float so = __shfl(sume, src, 64);
        if (lane < half) {
            sume += so;
#pragma unroll
            for (int t = 0; t < 8; ++t)
                if (Ko[t] < K[7]) ins8m(Ko[t], Lo[t], K, L);
        }
    }
}

// ---------------------------------------------------------------------------
// Main: dual GEMM (logits+dists, bf16) with swapped MFMA operands; each lane
// owns TWO flat-rows' online softmax-sum + top-8 in registers (2 row-frags
// per wave -> each B fragment feeds 4 MFMAs, halving L1 traffic). Atom axis
// split 4-way across the block's waves. Block = 32 rows x 4 atom-quarters,
// grid 1024. Per-iter rb/dn tables prefetched as f32x4 (hidden under MFMA).
__global__ __launch_bounds__(256, 2) void vq_main(
    const float* __restrict__ z_e, const unsigned short* __restrict__ Bs,
    const float* __restrict__ rep_b, const float* __restrict__ dnorm,
    float* __restrict__ rep_sparse, int* __restrict__ idx_out,
    float* __restrict__ w_out, int* __restrict__ counts)
{
    __shared__ __align__(16) float rbS[1024];
    __shared__ __align__(16) float dnS[1024];
    __shared__ unsigned long long mK[3][32][8];
    __shared__ float mL[3][32][8];
    __shared__ float mS[3][32];

    const int tid = threadIdx.x;
    const int lane = tid & 63, w = tid >> 6;     // w = atom quarter
    const int c = lane & 15, lg = lane >> 4;
    const int row0 = blockIdx.x * 32;
    const int bb = row0 >> 10, hw0 = row0 & 1023;

    for (int i = tid; i < 1024; i += 256) { rbS[i] = rep_b[i]; dnS[i] = dnorm[i]; }

    const char* pL = (const char*)Bs;             // rep plane  [8][1024][32]
    const char* pD = (const char*)Bs + 524288;    // dict plane
    const int abase = w << 8;                     // 256 atoms per quarter

    // first B tile (atoms abase..abase+15): frag = 16 atoms x 32k, 1KB each
    bf16x8 bL[8], bD[8];
    {
        const int off = ((abase + c) << 6) + (lg << 4);
#pragma unroll
        for (int kc = 0; kc < 8; ++kc) {
            bL[kc] = *(const bf16x8*)(pL + ((size_t)kc << 16) + off);
            bD[kc] = *(const bf16x8*)(pD + ((size_t)kc << 16) + off);
        }
    }

    // A: rows rf*16 + c (rf=0,1), k = kc*32 + lg*8 + e, bf16 1-term
    bf16x8 A0[8], A1[8];
    {
        const float* zb = z_e + (size_t)bb * 262144 + hw0 + c;
#pragma unroll
        for (int kc = 0; kc < 8; ++kc) {
            float f0[8], f1[8];
#pragma unroll
            for (int e = 0; e < 8; ++e) {
                const float* p = zb + (size_t)(kc * 32 + lg * 8 + e) * 1024;
                f0[e] = p[0];
                f1[e] = p[16];
            }
#pragma unroll
            for (int e = 0; e < 8; ++e) {
                A0[kc][e] = (short)bf16rne(f0[e]);
                A1[kc][e] = (short)bf16rne(f1[e]);
            }
        }
    }
    __syncthreads();   // tables staged

    // per-lane online state: frag0 = row c, frag1 = row 16+c (part lg, quarter w)
    unsigned kd0[8], iv0[8], kd1[8], iv1[8];
    float lv0[8], lv1[8];
    float se0 = 0.f, se1 = 0.f;
#pragma unroll
    for (int j = 0; j < 8; ++j) {
        kd0[j] = 0xFFFFFFFFu; iv0[j] = 0u; lv0[j] = 0.f;
        kd1[j] = 0xFFFFFFFFu; iv1[j] = 0u; lv1[j] = 0.f;
    }

    for (int it = 0; it < 16; ++it) {
        // table prefetch for this iter's 4 atoms (hidden under MFMA block)
        const int tb = abase + (it << 4) + (lg << 2);
        const f32x4 rbv = *(const f32x4*)&rbS[tb];
        const f32x4 dnv = *(const f32x4*)&dnS[tb];

        f32x4 aL0 = {0.f,0.f,0.f,0.f}, aD0 = {0.f,0.f,0.f,0.f};
        f32x4 aL1 = {0.f,0.f,0.f,0.f}, aD1 = {0.f,0.f,0.f,0.f};
        // D[atom][flatrow]: A-operand = atom frag, B-operand = flat-row frag
#pragma unroll
        for (int kc = 0; kc < 8; ++kc) {
            aL0 = __builtin_amdgcn_mfma_f32_16x16x32_bf16(bL[kc], A0[kc], aL0, 0, 0, 0);
            aD0 = __builtin_amdgcn_mfma_f32_16x16x32_bf16(bD[kc], A0[kc], aD0, 0, 0, 0);
            aL1 = __builtin_amdgcn_mfma_f32_16x16x32_bf16(bL[kc], A1[kc], aL1, 0, 0, 0);
            aD1 = __builtin_amdgcn_mfma_f32_16x16x32_bf16(bD[kc], A1[kc], aD1, 0, 0, 0);
        }

        // prefetch next B tile (regs free after last MFMA read)
        if (it < 15) {
            const int off = ((abase + (it + 1) * 16 + c) << 6) + (lg << 4);
#pragma unroll
            for (int kc = 0; kc < 8; ++kc) {
                bL[kc] = *(const bf16x8*)(pL + ((size_t)kc << 16) + off);
                bD[kc] = *(const bf16x8*)(pD + ((size_t)kc << 16) + off);
            }
        }

        // in-register scan: atoms tb+q for rows c (frag0) and 16+c (frag1)
#pragma unroll
        for (int q = 0; q < 4; ++q) {
            const unsigned atom = (unsigned)(tb + q);
            const float l0 = aL0[q] + rbv[q];
            const float l1 = aL1[q] + rbv[q];
            const float v0 = dnv[q] - 2.0f * aD0[q];
            const float v1 = dnv[q] - 2.0f * aD1[q];
            se0 += __expf(l0);
            se1 += __expf(l1);
            unsigned u0 = __float_as_uint(v0);
            u0 ^= ((unsigned)((int)u0 >> 31) | 0x80000000u);
            unsigned u1 = __float_as_uint(v1);
            u1 ^= ((unsigned)((int)u1 >> 31) | 0x80000000u);
            if (u0 < kd0[7]) ins8(u0, l0, atom, kd0, lv0, iv0);
            if (u1 < kd1[7]) ins8(u1, l1, atom, kd1, lv1, iv1);
        }
    }

    // ---- in-wave merges (parts lg -> lanes 0..15), both frags
    unsigned long long K0[8], K1[8];
    float L0[8], L1[8];
#pragma unroll
    for (int j = 0; j < 8; ++j) {
        K0[j] = ((unsigned long long)kd0[j] << 32) | iv0[j]; L0[j] = lv0[j];
        K1[j] = ((unsigned long long)kd1[j] << 32) | iv1[j]; L1[j] = lv1[j];
    }
    wave_merge(lane, K0, L0, se0);
    wave_merge(lane, K1, L1, se1);
    // lanes 0..15: frag0 = row c, frag1 = row 16+c (this wave's atom quarter)

    // quarters 1..3 publish to LDS
    if (w >= 1 && lane < 16) {
#pragma unroll
        for (int j = 0; j < 8; ++j) {
            mK[w - 1][c][j] = K0[j];      mL[w - 1][c][j] = L0[j];
            mK[w - 1][16 + c][j] = K1[j]; mL[w - 1][16 + c][j] = L1[j];
        }
        mS[w - 1][c] = se0;
        mS[w - 1][16 + c] = se1;
    }
    __syncthreads();

    // zero-fill this block's 32 rows of rep_sparse (replaces memset kernel)
    {
        float4 z4 = {0.f, 0.f, 0.f, 0.f};
        float4* rp4 = (float4*)rep_sparse + (size_t)row0 * (NATOMS / 4) + tid;
        for (int r = 0; r < 32; ++r)
            rp4[(size_t)r * (NATOMS / 4)] = z4;
    }
    __syncthreads();   // zero stores drained before scatter

    // quarter-0 wave: merge other quarters, finalize, scatter (2 rows/lane)
    if (w == 0 && lane < 16) {
        auto finish = [&](unsigned long long (&K)[8], float (&L)[8], float sume, int rloc) {
            for (int p = 0; p < 3; ++p)
                for (int t = 0; t < 8; ++t) {
                    const unsigned long long ck = mK[p][rloc][t];
                    if (ck < K[7]) ins8m(ck, mL[p][rloc][t], K, L);
                }
            sume += mS[0][rloc] + mS[1][rloc] + mS[2][rloc];
            const int row = row0 + rloc;
            const float inv = 0.125f / sume;   // softmax / SPARSITY
#pragma unroll
            for (int j = 0; j < 8; ++j) {
                const int gidx = (int)(K[j] & 0x3ffull);
                const float wv = __expf(L[j]) * inv;
                idx_out[row * 8 + j] = gidx;
                w_out[row * 8 + j] = wv;
                rep_sparse[(size_t)row * NATOMS + gidx] = wv;
                atomicAdd(&counts[gidx], 1);
            }
        };
        finish(K0, L0, se0, c);
        finish(K1, L1, se1, 16 + c);
    }
}

// ---------------------------------------------------------------------------
// Reconstruct z_dl, write z_st (NCHW), accumulate squared-error partials.
__global__ __launch_bounds__(256, 2) void vq_recon(
    const float* __restrict__ z_e, const float* __restrict__ dict_w,
    const int* __restrict__ idx_in, const float* __restrict__ w_in,
    float* __restrict__ z_st, float* __restrict__ partials)
{
    __shared__ float zdl[32][257];
    __shared__ float red[256];
    const int tid = threadIdx.x;
    const int row0 = blockIdx.x * 32;

    for (int r = 0; r < 32; ++r) {
        const int row = row0 + r;
        float acc = 0.f;
#pragma unroll
        for (int j = 0; j < 8; ++j) {
            const int ix = idx_in[row * 8 + j];
            const float wv = w_in[row * 8 + j];
            acc = fmaf(wv, dict_w[(size_t)ix * DIMD + tid], acc);
        }
        zdl[r][tid] = acc;
    }
    __syncthreads();

    const int bb = row0 >> 10, hw0 = row0 & 1023;
    const float* zb = z_e + (size_t)bb * (DIMD * 1024) + hw0;
    float* ob = z_st + (size_t)bb * (DIMD * 1024) + hw0;
    const int m = tid & 31, dg = tid >> 5;
    float sacc = 0.f;
    for (int itr = 0; itr < 32; ++itr) {
        const int d = itr * 8 + dg;
        const float ze = zb[(size_t)d * 1024 + m];
        const float zd = zdl[m][d];
        const float diff = zd - ze;
        ob[(size_t)d * 1024 + m] = ze + diff;   // reference rounding path
        sacc = fmaf(diff, diff, sacc);
    }
    red[tid] = sacc;
    __syncthreads();
    for (int s = 128; s > 0; s >>= 1) {
        if (tid < s) red[tid] += red[tid + s];
        __syncthreads();
    }
    if (tid == 0) partials[blockIdx.x] = red[0];
}

// ---------------------------------------------------------------------------
// Finalize: loss and perplexity (deterministic fixed-order reductions)
__global__ void vq_final(const float* __restrict__ partials,
                         const int* __restrict__ counts,
                         float* __restrict__ out_loss, float* __restrict__ out_perp)
{
    __shared__ double dred[256];
    __shared__ float fred[256];
    const int tid = threadIdx.x;
    double s = 0.0;
    for (int i = tid; i < 1024; i += 256) s += (double)partials[i];
    dred[tid] = s;
    __syncthreads();
    for (int st = 128; st > 0; st >>= 1) {
        if (tid < st) dred[tid] += dred[tid + st];
        __syncthreads();
    }
    float ps = 0.f;
    for (int i = tid; i < NATOMS; i += 256) {
        const float p = (float)counts[i] * (1.0f / 262144.0f);
        ps += p * logf(p + 1e-10f);
    }
    fred[tid] = ps;
    __syncthreads();
    for (int st = 128; st > 0; st >>= 1) {
        if (tid < st) fred[tid] += fred[tid + st];
        __syncthreads();
    }
    if (tid == 0) {
        *out_loss = 0.25f * (float)(dred[0] / 8388608.0);
        *out_perp = expf(-fred[0]);
    }
}

// ---------------------------------------------------------------------------
extern "C" void kernel_launch(void* const* d_in, const int* in_sizes, int n_in,
                              void* d_out, int out_size, void* d_ws, size_t ws_size,
                              hipStream_t stream) {
    const float* z_e    = (const float*)d_in[0];
    const float* dict_w = (const float*)d_in[1];
    const float* rep_w  = (const float*)d_in[2];
    const float* rep_b  = (const float*)d_in[3];

    float* out = (float*)d_out;
    float* out_loss   = out;                      // [0]
    float* z_st       = out + 1;                  // [1 .. 8388608]
    float* out_perp   = out + 1 + 8388608;        // [8388609]
    float* rep_sparse = out + 2 + 8388608;        // [8388610 ..] 32768x1024

    // Bs scratch (1 MB, 2 planes) parked INSIDE the z_st output region
    // (offset 16 MB). vq_recon rewrites all of z_st after vq_main finishes,
    // so no live data is clobbered and nothing leaks across calls.
    unsigned short* Bs = (unsigned short*)((((uintptr_t)(z_st + 4194304)) + 255) & ~(uintptr_t)255);

    char* ws = (char*)d_ws;
    int*   idx_out  = (int*)ws;                             // 1 MB
    float* w_out    = (float*)(ws + (1 << 20));             // 1 MB
    int*   counts   = (int*)(ws + (2 << 20));               // 4 KB
    float* dnorm    = (float*)(ws + (2 << 20) + 4096);      // 4 KB
    float* partials = (float*)(ws + (2 << 20) + 8192);      // 4 KB

    (void)hipMemsetAsync(counts, 0, NATOMS * sizeof(int), stream);

    vq_bprep<<<32, 256, 0, stream>>>(rep_w, dict_w, Bs, dnorm);
    vq_main<<<NROWS / 32, 256, 0, stream>>>(z_e, Bs, rep_b, dnorm,
                                            rep_sparse, idx_out, w_out, counts);
    vq_recon<<<NROWS / 32, 256, 0, stream>>>(z_e, dict_w, idx_out, w_out, z_st, partials);
    vq_final<<<1, 256, 0, stream>>>(partials, counts, out_loss, out_perp);
}